// Round 2
// baseline (426.845 us; speedup 1.0000x reference)
//
#include <hip/hip_runtime.h>
#include <hip/hip_bf16.h>
#include <math.h>

typedef __hip_bfloat16 bf16;
typedef short s16x8 __attribute__((ext_vector_type(8)));
typedef float f32x4 __attribute__((ext_vector_type(4)));

#define NQ 200
#define SEQ 8
#define DM 2048
#define OUTD 1152
#define LT 28
#define M_ALL 6300
#define SM 5600
#define SN_PAD 768
#define ATT_STRIDE 720
#define N2 2304          // W viewed as [2304, 2048]
#define KP 160
#define CH_Q 50
#define CH_ROWS 1400
#define CH_MPAD 1408
#define ABLK 144         // attn per-class column block (16B-aligned)

__device__ __forceinline__ float bf2f(bf16 v) { return __bfloat162float(v); }
__device__ __forceinline__ bf16 f2bf(float v) { return __float2bfloat16(v); }
__device__ __forceinline__ float ubits2f(unsigned int u16) {
    unsigned int i = u16 << 16;
    float f; __builtin_memcpy(&f, &i, 4); return f;
}
__device__ __forceinline__ unsigned short f2bits(float f) {
    bf16 b = __float2bfloat16(f);
    unsigned short u; __builtin_memcpy(&u, &b, 2); return u;
}

__device__ const int TUP_A[LT] = {0,0,0,0,0,0,0,1,1,1,1,1,1,2,2,2,2,2,3,3,3,3,4,4,4,5,5,6};
__device__ const int TUP_B[LT] = {1,2,3,4,5,6,7,2,3,4,5,6,7,3,4,5,6,7,4,5,6,7,5,6,7,6,7,7};

// ---------------------------------------------------------------------------
// fused weight convert: [k_w | v_w] fp32 -> bf16 (2 x 1,179,648 float4)
// ---------------------------------------------------------------------------
__global__ __launch_bounds__(256) void wconv2_k(const float4* __restrict__ kw,
                                                const float4* __restrict__ vw,
                                                ushort4* __restrict__ o) {
    int i = blockIdx.x * 256 + threadIdx.x;     // 0 .. 2,359,295
    float4 v = (i < 1179648) ? kw[i] : vw[i - 1179648];
    ushort4 r;
    r.x = f2bits(v.x); r.y = f2bits(v.y); r.z = f2bits(v.z); r.w = f2bits(v.w);
    o[i] = r;
}

// ---------------------------------------------------------------------------
// pe table: pe[s][d], 8 x 2048 fp32 (trig computed once, not 1800x)
// ---------------------------------------------------------------------------
__global__ __launch_bounds__(256) void pe_k(float* __restrict__ pe) {
    int i = blockIdx.x * 256 + threadIdx.x;     // 0 .. 16383
    int s = i >> 11, d = i & 2047;
    float dv = expf((float)(d & ~1) * (-9.210340371976184f / 2048.0f));
    float ang = (float)s * dv;
    pe[i] = (d & 1) ? cosf(ang) * 0.1f : sinf(ang) * 0.1f;
}

// ---------------------------------------------------------------------------
// pexb[r][d] = fp32 src[n][s][d] + pe[s][d] -> bf16 (1800 rows, vectorized)
// ---------------------------------------------------------------------------
__global__ __launch_bounds__(256) void pex_k(const float* __restrict__ sup,
                                             const float* __restrict__ qry,
                                             const float* __restrict__ pe,
                                             bf16* __restrict__ pexb) {
    int r = blockIdx.x, t = threadIdx.x;
    int n, s;
    const float* src;
    if (r < 200) { n = r >> 3; s = r & 7; src = sup; }
    else { int rr = r - 200; n = rr >> 3; s = rr & 7; src = qry; }
    const float4* row = (const float4*)(src + ((size_t)n * SEQ + s) * DM);
    const float4* per = (const float4*)(pe + (size_t)s * DM);
    ushort4* orow = (ushort4*)(pexb + (size_t)r * DM);
    for (int d = t; d < DM / 4; d += 256) {
        float4 a = row[d], p = per[d];
        ushort4 o;
        o.x = f2bits(a.x + p.x); o.y = f2bits(a.y + p.y);
        o.z = f2bits(a.z + p.z); o.w = f2bits(a.w + p.w);
        orow[d] = o;
    }
}

// ---------------------------------------------------------------------------
// Generic MFMA bf16 GEMM: C = scale*A*B^T; z shifts A/B/C by aZ/bZ/cZ elems.
// Staging via global_load_lds (16B DMA) + explicit 2-phase double buffer:
// STAGE(next tile) is issued BEFORE ds_read+MFMA of the current tile, and the
// per-iteration __syncthreads() drains vmcnt -> the staged buffer is ready.
// Four SEPARATE __shared__ arrays + compile-time buffer alternation (2 steps
// per loop body) so alias analysis proves staged-buffer != read-buffer and
// inserts no vmcnt wait before the ds_reads.
// LDS slot layout per buffer: [4 kq][128 rows][8 half]; lane stages slot t
// (kq=t>>7,row=t&127) and slot 256+t; per-lane GLOBAL addr carries the
// row/kq permutation (dest = wave-uniform base + lane*16 as HW requires).
// All A/B bases, lda/ldb and z-shifts must be 16B-aligned.
// C rows >= mlim are not stored (M-pad garbage containment).
// ---------------------------------------------------------------------------
__global__ __launch_bounds__(256) void gemm_bt(
    const bf16* __restrict__ A, int lda, size_t aZ,
    const bf16* __restrict__ B, int ldb, size_t bZ,
    float scale, bf16* __restrict__ C, int ldc, size_t cZ, int K, int mlim) {
    const unsigned short* Ag0 = (const unsigned short*)A + aZ * blockIdx.z;
    const unsigned short* Bg0 = (const unsigned short*)B + bZ * blockIdx.z;
    const size_t cbase = cZ * blockIdx.z;
    const int tile_m = blockIdx.x * 128, tile_n = blockIdx.y * 128;
    __shared__ unsigned short As0[4096];  // 8 KB each; 32 KB total
    __shared__ unsigned short As1[4096];
    __shared__ unsigned short Bs0[4096];
    __shared__ unsigned short Bs1[4096];
    const int t = threadIdx.x, lane = t & 63;
    const int wave = t >> 6;
    const int wm = (wave & 1) * 64, wn = (wave >> 1) * 64;
    const int fr = lane & 15, quad = lane >> 4;

    // staging addresses: slot t covers kq in {0,1}; slot 256+t covers {2,3}
    const int rowS = t & 127, kqS = t >> 7;
    const unsigned short* gA = Ag0 + (size_t)(tile_m + rowS) * lda + kqS * 8;
    const unsigned short* gB = Bg0 + (size_t)(tile_n + rowS) * ldb + kqS * 8;

    f32x4 acc[4][4];
#pragma unroll
    for (int i = 0; i < 4; i++)
#pragma unroll
        for (int j = 0; j < 4; j++) acc[i][j] = {0.f, 0.f, 0.f, 0.f};

#define STAGE(AS, BS, k0) do {                                                  \
    __builtin_amdgcn_global_load_lds(gA + (k0),      &AS[t * 8],        16, 0, 0); \
    __builtin_amdgcn_global_load_lds(gA + (k0) + 16, &AS[2048 + t * 8], 16, 0, 0); \
    __builtin_amdgcn_global_load_lds(gB + (k0),      &BS[t * 8],        16, 0, 0); \
    __builtin_amdgcn_global_load_lds(gB + (k0) + 16, &BS[2048 + t * 8], 16, 0, 0); \
  } while (0)

#define COMPUTE(AS, BS) do {                                                    \
    s16x8 af[4], bfv[4];                                                        \
    _Pragma("unroll")                                                           \
    for (int i = 0; i < 4; i++)                                                 \
        af[i] = *(const s16x8*)&AS[(quad * 128 + wm + i * 16 + fr) * 8];        \
    _Pragma("unroll")                                                           \
    for (int j = 0; j < 4; j++)                                                 \
        bfv[j] = *(const s16x8*)&BS[(quad * 128 + wn + j * 16 + fr) * 8];       \
    _Pragma("unroll")                                                           \
    for (int i = 0; i < 4; i++)                                                 \
    _Pragma("unroll")                                                           \
        for (int j = 0; j < 4; j++)                                             \
            acc[i][j] = __builtin_amdgcn_mfma_f32_16x16x32_bf16(af[i], bfv[j], acc[i][j], 0, 0, 0); \
  } while (0)

    const int nIter = K >> 5;              // K-step tiles of 32
    STAGE(As0, Bs0, 0);                    // tile 0 -> buf0
    __syncthreads();
    int it = 1;
    for (; it + 1 < nIter; it += 2) {      // tile i lives in buf(i&1)
        STAGE(As1, Bs1, it * 32);          // issue next tile (odd -> buf1)
        COMPUTE(As0, Bs0);                 // compute current (even)
        __syncthreads();                   // drains vmcnt: buf1 ready
        STAGE(As0, Bs0, (it + 1) * 32);    // issue (even -> buf0)
        COMPUTE(As1, Bs1);
        __syncthreads();
    }
    if (it < nIter) {                      // odd tail tile (it odd)
        STAGE(As1, Bs1, it * 32);
        COMPUTE(As0, Bs0);
        __syncthreads();
        COMPUTE(As1, Bs1);
    } else {
        COMPUTE(As0, Bs0);
    }
#undef STAGE
#undef COMPUTE

    const int rb = quad * 4;
#pragma unroll
    for (int i = 0; i < 4; i++)
#pragma unroll
        for (int j = 0; j < 4; j++) {
            const int col = tile_n + wn + j * 16 + fr;
#pragma unroll
            for (int r = 0; r < 4; r++) {
                const int row = tile_m + wm + i * 16 + rb + r;
                if (row < mlim)
                    C[cbase + (size_t)row * ldc + col] = f2bf(acc[i][j][r] * scale);
            }
        }
}

// ---------------------------------------------------------------------------
// combine_k: ks[m][n] = LN(Yk[ra][2n] + Yk[rb][2n+1] + kb[n])
// ---------------------------------------------------------------------------
__global__ __launch_bounds__(256) void combine_k(
    const unsigned int* __restrict__ Yk, const float* __restrict__ kb,
    const float* __restrict__ lng, const float* __restrict__ lnb,
    bf16* __restrict__ ks) {
    const int m = blockIdx.x, t = threadIdx.x, lane = t & 63, wave = t >> 6;
    int mm = m < 700 ? m : m - 700;
    int base = m < 700 ? 0 : 200;
    int nsamp = mm / LT, l = mm - nsamp * LT;
    const unsigned int* ya = Yk + (size_t)(base + nsamp * 8 + TUP_A[l]) * (N2 / 2);
    const unsigned int* yb = Yk + (size_t)(base + nsamp * 8 + TUP_B[l]) * (N2 / 2);
    float vals[5];
    int cnt = 0;
    float s = 0.f, s2 = 0.f;
    for (int n = t; n < OUTD; n += 256) {
        unsigned int ua = ya[n], ub = yb[n];
        float vk = ubits2f(ua & 0xFFFFu) + ubits2f(ub >> 16) + kb[n];
        vals[cnt++] = vk;
        s += vk; s2 += vk * vk;
    }
    for (int o = 32; o > 0; o >>= 1) { s += __shfl_xor(s, o); s2 += __shfl_xor(s2, o); }
    __shared__ float r1[4], r2[4];
    if (lane == 0) { r1[wave] = s; r2[wave] = s2; }
    __syncthreads();
    s = r1[0] + r1[1] + r1[2] + r1[3];
    s2 = r2[0] + r2[1] + r2[2] + r2[3];
    float mu = s * (1.f / OUTD);
    float var = s2 * (1.f / OUTD) - mu * mu;
    float inv = rsqrtf(fmaxf(var, 0.f) + 1e-5f);
    cnt = 0;
    for (int n = t; n < OUTD; n += 256)
        ks[(size_t)m * OUTD + n] = f2bf((vals[cnt++] - mu) * inv * lng[n] + lnb[n]);
}

// ---------------------------------------------------------------------------
// combine_v: vs[m][n] = Yv[ra][2n] + Yv[rb][2n+1] + vb[n]
// ---------------------------------------------------------------------------
__global__ __launch_bounds__(256) void combine_v(
    const unsigned int* __restrict__ Yv, const float* __restrict__ vb,
    bf16* __restrict__ vs) {
    const int m = blockIdx.x, t = threadIdx.x;
    int mm = m < 700 ? m : m - 700;
    int base = m < 700 ? 0 : 200;
    int nsamp = mm / LT, l = mm - nsamp * LT;
    const unsigned int* ya = Yv + (size_t)(base + nsamp * 8 + TUP_A[l]) * (N2 / 2);
    const unsigned int* yb = Yv + (size_t)(base + nsamp * 8 + TUP_B[l]) * (N2 / 2);
    for (int n = t; n < OUTD; n += 256) {
        unsigned int ua = ya[n], ub = yb[n];
        vs[(size_t)m * OUTD + n] =
            f2bf(ubits2f(ua & 0xFFFFu) + ubits2f(ub >> 16) + vb[n]);
    }
}

// ---------------------------------------------------------------------------
// softmax over 5 blocks of 140 support cols; attn laid out as 5 x 144-col
// blocks (16B-aligned per class); cols 140..143 of each block zeroed.
// ---------------------------------------------------------------------------
__global__ __launch_bounds__(256) void softmax_k(const bf16* __restrict__ sc,
                                                 bf16* __restrict__ attn) {
    int row = blockIdx.x, t = threadIdx.x, lane = t & 63, wave = t >> 6;
    __shared__ float redm[4], reds[4];
    for (int w = 0; w < 5; w++) {
        float v = (t < 140) ? bf2f(sc[(size_t)row * SN_PAD + w * 140 + t]) : -3.0e38f;
        float m = v;
        for (int o = 32; o > 0; o >>= 1) m = fmaxf(m, __shfl_xor(m, o));
        if (lane == 0) redm[wave] = m;
        __syncthreads();
        m = fmaxf(fmaxf(redm[0], redm[1]), fmaxf(redm[2], redm[3]));
        float e = (t < 140) ? __expf(v - m) : 0.f;
        float s = e;
        for (int o = 32; o > 0; o >>= 1) s += __shfl_xor(s, o);
        if (lane == 0) reds[wave] = s;
        __syncthreads();
        s = reds[0] + reds[1] + reds[2] + reds[3];
        if (t < 140) attn[(size_t)row * ATT_STRIDE + w * ABLK + t] = f2bf(e / s);
        else if (t < ABLK) attn[(size_t)row * ATT_STRIDE + w * ABLK + t] = f2bf(0.f);
        __syncthreads();
    }
}

// ---------------------------------------------------------------------------
// vsp[w][d][j] = vs[w*140+j][d] (j>=140 -> 0); block 0 also zeroes gbuf
// ---------------------------------------------------------------------------
__global__ __launch_bounds__(256) void vspad_k(const bf16* __restrict__ vs,
                                               bf16* __restrict__ vp,
                                               float* __restrict__ gbuf) {
    int idx = blockIdx.x * 256 + threadIdx.x;
    if (blockIdx.x == 0)
        for (int i = threadIdx.x; i < NQ * 21; i += 256) gbuf[i] = 0.f;
    if (idx >= 5 * OUTD * KP) return;
    int j = idx % KP;
    int rest = idx / KP;
    int dcol = rest % OUTD;
    int w = rest / OUTD;
    vp[idx] = (j < 140) ? vs[(size_t)(w * 140 + j) * OUTD + dcol] : f2bf(0.f);
}

// ---------------------------------------------------------------------------
// Gram reduce over a proto chunk -> 21 sufficient stats per query
// ---------------------------------------------------------------------------
__global__ __launch_bounds__(256) void gramred_k(const bf16* __restrict__ protoc,
                                                 const bf16* __restrict__ vs,
                                                 float* __restrict__ gbuf,
                                                 int row0, int q0) {
    const int ql = blockIdx.x;
    const int lg = blockIdx.y;
    const int t = threadIdx.x, lane = t & 63, wave = t >> 6;
    const size_t PZ = (size_t)CH_MPAD * OUTD;
    float g[15] = {0.f};
    float h[5] = {0.f, 0.f, 0.f, 0.f, 0.f};
    float e = 0.f;
    for (int idx = t; idx < 4 * OUTD; idx += 256) {
        int l = lg * 4 + idx / OUTD;
        int d = idx - (idx / OUTD) * OUTD;
        size_t ml = (size_t)(ql * LT + l) * OUTD + d;
        float pv[5];
#pragma unroll
        for (int w = 0; w < 5; w++) pv[w] = bf2f(protoc[w * PZ + ml]);
        float v = bf2f(vs[(size_t)(700 + row0 + ql * LT + l) * OUTD + d]);
        e += v * v;
        int c = 0;
#pragma unroll
        for (int a = 0; a < 5; a++) {
            h[a] += v * pv[a];
#pragma unroll
            for (int b = a; b < 5; b++) g[c++] += pv[a] * pv[b];
        }
    }
    float vals[21];
#pragma unroll
    for (int k = 0; k < 15; k++) vals[k] = g[k];
#pragma unroll
    for (int k = 0; k < 5; k++) vals[15 + k] = h[k];
    vals[20] = e;
#pragma unroll
    for (int k = 0; k < 21; k++)
        for (int o = 32; o > 0; o >>= 1) vals[k] += __shfl_xor(vals[k], o);
    __shared__ float red[4][21];
    if (lane == 0)
#pragma unroll
        for (int k = 0; k < 21; k++) red[wave][k] = vals[k];
    __syncthreads();
    if (t < 21) {
        float s = red[0][t] + red[1][t] + red[2][t] + red[3][t];
        atomicAdd(&gbuf[(q0 + ql) * 21 + t], s);
    }
}

// ---------------------------------------------------------------------------
// out (fp32): per q -> 25 sim + 5 ori
// ---------------------------------------------------------------------------
__global__ __launch_bounds__(64) void out_k(const float* __restrict__ gbuf,
                                            float* __restrict__ out) {
    int q = blockIdx.x;
    if (threadIdx.x != 0) return;
    const float* r = gbuf + q * 21;
    float G[5][5];
    int c = 0;
    for (int a = 0; a < 5; a++)
        for (int b = a; b < 5; b++) { G[a][b] = r[c]; G[b][a] = r[c]; c++; }
    float e = r[20];
    float nrm[5];
    for (int a = 0; a < 5; a++) nrm[a] = sqrtf(fmaxf(G[a][a], 0.f));
    for (int a = 0; a < 5; a++)
        for (int b = 0; b < 5; b++)
            out[(size_t)q * 25 + a * 5 + b] = G[a][b] / fmaxf(nrm[a] * nrm[b], 1e-8f);
    for (int w = 0; w < 5; w++)
        out[5000 + (size_t)q * 5 + w] = -(e - 2.f * r[15 + w] + G[w][w]) * (1.f / 28.f);
}

// ---------------------------------------------------------------------------
extern "C" void kernel_launch(void* const* d_in, const int* in_sizes, int n_in,
                              void* d_out, int out_size, void* d_ws, size_t ws_size,
                              hipStream_t stream) {
    const float* sup = (const float*)d_in[0];
    // d_in[1] = support_labels int32 — unused (sorted equal-shot)
    const float* qry = (const float*)d_in[2];
    const float* k_w = (const float*)d_in[3];
    const float* k_b = (const float*)d_in[4];
    const float* v_w = (const float*)d_in[5];
    const float* v_b = (const float*)d_in[6];
    const float* lng = (const float*)d_in[7];
    const float* lnb = (const float*)d_in[8];
    (void)in_sizes; (void)n_in; (void)out_size; (void)ws_size;

    // layout (bytes), peak 49,421,728 (<= verified ws_size >= 54.5 MB):
    //   pexb   @0           7,864,320 (1920 rows; 1800 real)  dead after proj
    //   wbf    @7,864,320  18,874,368 (k|v bf16)              dead after proj
    //   Yk     @26,738,688  8,294,400 (1800x2304)             dead after comb_k
    //   Yv     @35,033,088  8,294,400                         dead after comb_v
    //   ks     @0          14,588,928 (6332 rows; 6300 real)  dead after scores
    //   vs     @16,220,160 14,515,200 (6300 rows)             live to end
    //   sc     @30,735,360  8,650,752 (over dead Yk/Yv head)  dead after softmax
    //   vsp    @39,386,112  1,843,200
    //   attn   @41,229,312  8,110,080 (5632 rows x 720; 5 x 144-col blocks)
    //   gbuf   @49,339,392     16,800
    //   pe     @49,356,192     65,536 (8x2048 fp32 table)
    //   protoc @0          16,220,160 (over dead ks, after scores)
    char* ws = (char*)d_ws;
    bf16* pexb   = (bf16*)(ws + 0);
    bf16* wbf    = (bf16*)(ws + 7864320);
    bf16* Yk     = (bf16*)(ws + 26738688);
    bf16* Yv     = (bf16*)(ws + 35033088);
    bf16* ks     = (bf16*)(ws + 0);
    bf16* vs     = (bf16*)(ws + 16220160);
    bf16* sc     = (bf16*)(ws + 30735360);
    bf16* vsp    = (bf16*)(ws + 39386112);
    bf16* attn   = (bf16*)(ws + 41229312);
    float* gbuf  = (float*)(ws + 49339392);
    float* pe    = (float*)(ws + 49356192);
    bf16* protoc = (bf16*)(ws + 0);

    pe_k<<<dim3(64), dim3(256), 0, stream>>>(pe);
    pex_k<<<dim3(1800), dim3(256), 0, stream>>>(sup, qry, pe, pexb);
    wconv2_k<<<dim3(9216), dim3(256), 0, stream>>>(
        (const float4*)k_w, (const float4*)v_w, (ushort4*)wbf);

    // fused K+V projection: z in {k,v}; Y[1800,2304] = pexb @ W_view^T
    gemm_bt<<<dim3(15, 18, 2), dim3(256), 0, stream>>>(
        pexb, DM, 0, wbf, DM, (size_t)4718592,
        1.0f, Yk, N2, (size_t)4147200, DM, 1800);

    combine_k<<<dim3(M_ALL), dim3(256), 0, stream>>>(
        (const unsigned int*)Yk, k_b, lng, lnb, ks);
    combine_v<<<dim3(M_ALL), dim3(256), 0, stream>>>(
        (const unsigned int*)Yv, v_b, vs);

    // scores: ks_q[5632,1152] @ ks_s[768,1152]^T / sqrt(1152)
    gemm_bt<<<dim3(44, 6, 1), dim3(256), 0, stream>>>(
        ks + (size_t)700 * OUTD, OUTD, 0, ks, OUTD, 0,
        0.029462782549439484f, sc, SN_PAD, 0, OUTD, 5632);

    vspad_k<<<dim3((5 * OUTD * KP + 255) / 256), dim3(256), 0, stream>>>(
        vs, vsp, gbuf);
    softmax_k<<<dim3(SM), dim3(256), 0, stream>>>(sc, attn);

    // proto chunks: 4 x 50 queries; per-class GEMM then Gram reduce
    // A = attn with 144-col class blocks (aZ=144, 16B-aligned); K=160 reads
    // spill 16 cols into the next block where vsp's zero columns kill them.
    for (int c = 0; c < 4; c++) {
        gemm_bt<<<dim3(11, 9, 5), dim3(256), 0, stream>>>(
            attn + (size_t)c * CH_ROWS * ATT_STRIDE, ATT_STRIDE, (size_t)ABLK,
            vsp, KP, (size_t)OUTD * KP,
            1.0f, protoc, OUTD, (size_t)CH_MPAD * OUTD, KP, CH_MPAD);
        gramred_k<<<dim3(CH_Q, 7), dim3(256), 0, stream>>>(
            protoc, vs, gbuf, c * CH_ROWS, c * CH_Q);
    }

    out_k<<<dim3(NQ), dim3(64), 0, stream>>>(gbuf, (float*)d_out);
}

// Round 3
// 376.507 us; speedup vs baseline: 1.1337x; 1.1337x over previous
//
#include <hip/hip_runtime.h>
#include <hip/hip_bf16.h>
#include <math.h>

typedef __hip_bfloat16 bf16;
typedef short s16x8 __attribute__((ext_vector_type(8)));
typedef float f32x4 __attribute__((ext_vector_type(4)));

#define NQ 200
#define SEQ 8
#define DM 2048
#define OUTD 1152
#define LT 28
#define M_ALL 6300
#define SM 5600
#define SN_PAD 768
#define ATT_STRIDE 720
#define N2 2304          // W viewed as [2304, 2048]
#define KP 160
#define CH_Q 50
#define CH_ROWS 1400
#define CH_MPAD 1408
#define ABLK 144         // attn per-class column block (16B-aligned)

__device__ __forceinline__ float bf2f(bf16 v) { return __bfloat162float(v); }
__device__ __forceinline__ bf16 f2bf(float v) { return __float2bfloat16(v); }
__device__ __forceinline__ float ubits2f(unsigned int u16) {
    unsigned int i = u16 << 16;
    float f; __builtin_memcpy(&f, &i, 4); return f;
}
__device__ __forceinline__ unsigned short f2bits(float f) {
    bf16 b = __float2bfloat16(f);
    unsigned short u; __builtin_memcpy(&u, &b, 2); return u;
}

__device__ const int TUP_A[LT] = {0,0,0,0,0,0,0,1,1,1,1,1,1,2,2,2,2,2,3,3,3,3,4,4,4,5,5,6};
__device__ const int TUP_B[LT] = {1,2,3,4,5,6,7,2,3,4,5,6,7,3,4,5,6,7,4,5,6,7,5,6,7,6,7,7};

// ---------------------------------------------------------------------------
// fused weight convert: [k_w | v_w] fp32 -> bf16 (2 x 1,179,648 float4)
// ---------------------------------------------------------------------------
__global__ __launch_bounds__(256) void wconv2_k(const float4* __restrict__ kw,
                                                const float4* __restrict__ vw,
                                                ushort4* __restrict__ o) {
    int i = blockIdx.x * 256 + threadIdx.x;     // 0 .. 2,359,295
    float4 v = (i < 1179648) ? kw[i] : vw[i - 1179648];
    ushort4 r;
    r.x = f2bits(v.x); r.y = f2bits(v.y); r.z = f2bits(v.z); r.w = f2bits(v.w);
    o[i] = r;
}

// ---------------------------------------------------------------------------
// pe table: pe[s][d], 8 x 2048 fp32 (trig computed once, not 1800x)
// ---------------------------------------------------------------------------
__global__ __launch_bounds__(256) void pe_k(float* __restrict__ pe) {
    int i = blockIdx.x * 256 + threadIdx.x;     // 0 .. 16383
    int s = i >> 11, d = i & 2047;
    float dv = expf((float)(d & ~1) * (-9.210340371976184f / 2048.0f));
    float ang = (float)s * dv;
    pe[i] = (d & 1) ? cosf(ang) * 0.1f : sinf(ang) * 0.1f;
}

// ---------------------------------------------------------------------------
// pexb[r][d] = fp32 src[n][s][d] + pe[s][d] -> bf16 (1800 rows, vectorized)
// ---------------------------------------------------------------------------
__global__ __launch_bounds__(256) void pex_k(const float* __restrict__ sup,
                                             const float* __restrict__ qry,
                                             const float* __restrict__ pe,
                                             bf16* __restrict__ pexb) {
    int r = blockIdx.x, t = threadIdx.x;
    int n, s;
    const float* src;
    if (r < 200) { n = r >> 3; s = r & 7; src = sup; }
    else { int rr = r - 200; n = rr >> 3; s = rr & 7; src = qry; }
    const float4* row = (const float4*)(src + ((size_t)n * SEQ + s) * DM);
    const float4* per = (const float4*)(pe + (size_t)s * DM);
    ushort4* orow = (ushort4*)(pexb + (size_t)r * DM);
    for (int d = t; d < DM / 4; d += 256) {
        float4 a = row[d], p = per[d];
        ushort4 o;
        o.x = f2bits(a.x + p.x); o.y = f2bits(a.y + p.y);
        o.z = f2bits(a.z + p.z); o.w = f2bits(a.w + p.w);
        orow[d] = o;
    }
}

// ---------------------------------------------------------------------------
// Generic MFMA bf16 GEMM: C = scale*A*B^T; z shifts A/B/C by aZ/bZ/cZ elems.
// Register-staged (global->VGPR->LDS): VGPR destinations let the compiler
// pipeline loads across the barrier (gload_lds variants serialized on the
// conservative vmcnt drain and regressed 75->116/128us at this occupancy).
// Explicit 2-deep prefetch: two named register buffers (static indexing),
// loads for step s+2 issued right after step s's LDS turnover -> ~2 compute
// phases of latency slack.  Requires K >= 64 (all call sites: 2048/1152/160).
// XCD-chunked bijective block swizzle (T1/m204): blocks sharing a B-panel
// land on one XCD's private L2 (FETCH_SIZE was 4x compulsory without it).
// C rows >= mlim are not stored (M-pad garbage containment).
// ---------------------------------------------------------------------------
__global__ __launch_bounds__(256) void gemm_bt(
    const bf16* __restrict__ A, int lda, size_t aZ,
    const bf16* __restrict__ B, int ldb, size_t bZ,
    float scale, bf16* __restrict__ C, int ldc, size_t cZ, int K, int mlim) {
    // ---- XCD swizzle: logical tile id lg from hw block id (bijective) ----
    const int gx = gridDim.x, gy = gridDim.y;
    const int nwg = gx * gy * (int)gridDim.z;
    const int orig = ((int)blockIdx.z * gy + blockIdx.y) * gx + blockIdx.x;
    const int qc = nwg >> 3, rc = nwg & 7;
    const int xcd = orig & 7, sub = orig >> 3;
    const int lg = (xcd < rc ? xcd * (qc + 1) : rc * (qc + 1) + (xcd - rc) * qc) + sub;
    const int bx = lg % gx;
    const int rest = lg / gx;
    const int by = rest % gy, bz = rest / gy;

    const unsigned short* Ag0 = (const unsigned short*)A + aZ * bz;
    const unsigned short* Bg0 = (const unsigned short*)B + bZ * bz;
    const size_t cbase = cZ * bz;
    const int tile_m = bx * 128, tile_n = by * 128;
    __shared__ unsigned short As[4 * 128 * 8];
    __shared__ unsigned short Bs[4 * 128 * 8];
    const int t = threadIdx.x, lane = t & 63, wave = t >> 6;
    const int wm = (wave & 1) * 64, wn = (wave >> 1) * 64;
    const int srow = t >> 1, sq0 = (t & 1) * 2;
    const unsigned short* Ag = Ag0 + (size_t)(tile_m + srow) * lda + (t & 1) * 16;
    const unsigned short* Bg = Bg0 + (size_t)(tile_n + srow) * ldb + (t & 1) * 16;
    unsigned short* AsW0 = &As[((sq0 + 0) * 128 + srow) * 8];
    unsigned short* AsW1 = &As[((sq0 + 1) * 128 + srow) * 8];
    unsigned short* BsW0 = &Bs[((sq0 + 0) * 128 + srow) * 8];
    unsigned short* BsW1 = &Bs[((sq0 + 1) * 128 + srow) * 8];
    const int fr = lane & 15, quad = lane >> 4;

    f32x4 acc[4][4];
#pragma unroll
    for (int i = 0; i < 4; i++)
#pragma unroll
        for (int j = 0; j < 4; j++) acc[i][j] = {0.f, 0.f, 0.f, 0.f};

#define GLOAD(d0, d1, e0, e1, k0) do {                                          \
    d0 = *(const uint4*)(Ag + (k0));     d1 = *(const uint4*)(Ag + (k0) + 8);   \
    e0 = *(const uint4*)(Bg + (k0));     e1 = *(const uint4*)(Bg + (k0) + 8);   \
  } while (0)

#define LDSW(d0, d1, e0, e1) do {                                               \
    *(uint4*)AsW0 = d0; *(uint4*)AsW1 = d1;                                     \
    *(uint4*)BsW0 = e0; *(uint4*)BsW1 = e1;                                     \
  } while (0)

#define COMPUTE() do {                                                          \
    s16x8 af[4], bfv[4];                                                        \
    _Pragma("unroll")                                                           \
    for (int i = 0; i < 4; i++)                                                 \
        af[i] = *(const s16x8*)&As[(quad * 128 + wm + i * 16 + fr) * 8];        \
    _Pragma("unroll")                                                           \
    for (int j = 0; j < 4; j++)                                                 \
        bfv[j] = *(const s16x8*)&Bs[(quad * 128 + wn + j * 16 + fr) * 8];       \
    _Pragma("unroll")                                                           \
    for (int i = 0; i < 4; i++)                                                 \
    _Pragma("unroll")                                                           \
        for (int j = 0; j < 4; j++)                                             \
            acc[i][j] = __builtin_amdgcn_mfma_f32_16x16x32_bf16(af[i], bfv[j], acc[i][j], 0, 0, 0); \
  } while (0)

    const int nIter = K >> 5;              // K-step tiles of 32 (nIter >= 2)
    uint4 pa0, pa1, pb0, pb1;              // even-step buffer
    uint4 qa0, qa1, qb0, qb1;              // odd-step buffer
    GLOAD(pa0, pa1, pb0, pb1, 0);
    GLOAD(qa0, qa1, qb0, qb1, 32);
    for (int s = 0; s < nIter; s += 2) {   // all guards wave-uniform
        __syncthreads();                   // prev readers done
        LDSW(pa0, pa1, pb0, pb1);
        __syncthreads();                   // tile s visible
        if (s + 2 < nIter) GLOAD(pa0, pa1, pb0, pb1, (s + 2) * 32);
        COMPUTE();
        if (s + 1 < nIter) {
            __syncthreads();
            LDSW(qa0, qa1, qb0, qb1);
            __syncthreads();
            if (s + 3 < nIter) GLOAD(qa0, qa1, qb0, qb1, (s + 3) * 32);
            COMPUTE();
        }
    }
#undef GLOAD
#undef LDSW
#undef COMPUTE

    const int rb = quad * 4;
#pragma unroll
    for (int i = 0; i < 4; i++)
#pragma unroll
        for (int j = 0; j < 4; j++) {
            const int col = tile_n + wn + j * 16 + fr;
#pragma unroll
            for (int r = 0; r < 4; r++) {
                const int row = tile_m + wm + i * 16 + rb + r;
                if (row < mlim)
                    C[cbase + (size_t)row * ldc + col] = f2bf(acc[i][j][r] * scale);
            }
        }
}

// ---------------------------------------------------------------------------
// combine_k: ks[m][n] = LN(Yk[ra][2n] + Yk[rb][2n+1] + kb[n])
// ---------------------------------------------------------------------------
__global__ __launch_bounds__(256) void combine_k(
    const unsigned int* __restrict__ Yk, const float* __restrict__ kb,
    const float* __restrict__ lng, const float* __restrict__ lnb,
    bf16* __restrict__ ks) {
    const int m = blockIdx.x, t = threadIdx.x, lane = t & 63, wave = t >> 6;
    int mm = m < 700 ? m : m - 700;
    int base = m < 700 ? 0 : 200;
    int nsamp = mm / LT, l = mm - nsamp * LT;
    const unsigned int* ya = Yk + (size_t)(base + nsamp * 8 + TUP_A[l]) * (N2 / 2);
    const unsigned int* yb = Yk + (size_t)(base + nsamp * 8 + TUP_B[l]) * (N2 / 2);
    float vals[5];
    int cnt = 0;
    float s = 0.f, s2 = 0.f;
    for (int n = t; n < OUTD; n += 256) {
        unsigned int ua = ya[n], ub = yb[n];
        float vk = ubits2f(ua & 0xFFFFu) + ubits2f(ub >> 16) + kb[n];
        vals[cnt++] = vk;
        s += vk; s2 += vk * vk;
    }
    for (int o = 32; o > 0; o >>= 1) { s += __shfl_xor(s, o); s2 += __shfl_xor(s2, o); }
    __shared__ float r1[4], r2[4];
    if (lane == 0) { r1[wave] = s; r2[wave] = s2; }
    __syncthreads();
    s = r1[0] + r1[1] + r1[2] + r1[3];
    s2 = r2[0] + r2[1] + r2[2] + r2[3];
    float mu = s * (1.f / OUTD);
    float var = s2 * (1.f / OUTD) - mu * mu;
    float inv = rsqrtf(fmaxf(var, 0.f) + 1e-5f);
    cnt = 0;
    for (int n = t; n < OUTD; n += 256)
        ks[(size_t)m * OUTD + n] = f2bf((vals[cnt++] - mu) * inv * lng[n] + lnb[n]);
}

// ---------------------------------------------------------------------------
// combine_v: vs[m][n] = Yv[ra][2n] + Yv[rb][2n+1] + vb[n]
// ---------------------------------------------------------------------------
__global__ __launch_bounds__(256) void combine_v(
    const unsigned int* __restrict__ Yv, const float* __restrict__ vb,
    bf16* __restrict__ vs) {
    const int m = blockIdx.x, t = threadIdx.x;
    int mm = m < 700 ? m : m - 700;
    int base = m < 700 ? 0 : 200;
    int nsamp = mm / LT, l = mm - nsamp * LT;
    const unsigned int* ya = Yv + (size_t)(base + nsamp * 8 + TUP_A[l]) * (N2 / 2);
    const unsigned int* yb = Yv + (size_t)(base + nsamp * 8 + TUP_B[l]) * (N2 / 2);
    for (int n = t; n < OUTD; n += 256) {
        unsigned int ua = ya[n], ub = yb[n];
        vs[(size_t)m * OUTD + n] =
            f2bf(ubits2f(ua & 0xFFFFu) + ubits2f(ub >> 16) + vb[n]);
    }
}

// ---------------------------------------------------------------------------
// softmax over 5 blocks of 140 support cols; attn laid out as 5 x 144-col
// blocks (16B-aligned per class); cols 140..143 of each block zeroed.
// ---------------------------------------------------------------------------
__global__ __launch_bounds__(256) void softmax_k(const bf16* __restrict__ sc,
                                                 bf16* __restrict__ attn) {
    int row = blockIdx.x, t = threadIdx.x, lane = t & 63, wave = t >> 6;
    __shared__ float redm[4], reds[4];
    for (int w = 0; w < 5; w++) {
        float v = (t < 140) ? bf2f(sc[(size_t)row * SN_PAD + w * 140 + t]) : -3.0e38f;
        float m = v;
        for (int o = 32; o > 0; o >>= 1) m = fmaxf(m, __shfl_xor(m, o));
        if (lane == 0) redm[wave] = m;
        __syncthreads();
        m = fmaxf(fmaxf(redm[0], redm[1]), fmaxf(redm[2], redm[3]));
        float e = (t < 140) ? __expf(v - m) : 0.f;
        float s = e;
        for (int o = 32; o > 0; o >>= 1) s += __shfl_xor(s, o);
        if (lane == 0) reds[wave] = s;
        __syncthreads();
        s = reds[0] + reds[1] + reds[2] + reds[3];
        if (t < 140) attn[(size_t)row * ATT_STRIDE + w * ABLK + t] = f2bf(e / s);
        else if (t < ABLK) attn[(size_t)row * ATT_STRIDE + w * ABLK + t] = f2bf(0.f);
        __syncthreads();
    }
}

// ---------------------------------------------------------------------------
// vsp[w][d][j] = vs[w*140+j][d] (j>=140 -> 0); block 0 also zeroes gbuf
// ---------------------------------------------------------------------------
__global__ __launch_bounds__(256) void vspad_k(const bf16* __restrict__ vs,
                                               bf16* __restrict__ vp,
                                               float* __restrict__ gbuf) {
    int idx = blockIdx.x * 256 + threadIdx.x;
    if (blockIdx.x == 0)
        for (int i = threadIdx.x; i < NQ * 21; i += 256) gbuf[i] = 0.f;
    if (idx >= 5 * OUTD * KP) return;
    int j = idx % KP;
    int rest = idx / KP;
    int dcol = rest % OUTD;
    int w = rest / OUTD;
    vp[idx] = (j < 140) ? vs[(size_t)(w * 140 + j) * OUTD + dcol] : f2bf(0.f);
}

// ---------------------------------------------------------------------------
// Gram reduce over a proto chunk -> 21 sufficient stats per query
// ---------------------------------------------------------------------------
__global__ __launch_bounds__(256) void gramred_k(const bf16* __restrict__ protoc,
                                                 const bf16* __restrict__ vs,
                                                 float* __restrict__ gbuf,
                                                 int row0, int q0) {
    const int ql = blockIdx.x;
    const int lg = blockIdx.y;
    const int t = threadIdx.x, lane = t & 63, wave = t >> 6;
    const size_t PZ = (size_t)CH_MPAD * OUTD;
    float g[15] = {0.f};
    float h[5] = {0.f, 0.f, 0.f, 0.f, 0.f};
    float e = 0.f;
    for (int idx = t; idx < 4 * OUTD; idx += 256) {
        int l = lg * 4 + idx / OUTD;
        int d = idx - (idx / OUTD) * OUTD;
        size_t ml = (size_t)(ql * LT + l) * OUTD + d;
        float pv[5];
#pragma unroll
        for (int w = 0; w < 5; w++) pv[w] = bf2f(protoc[w * PZ + ml]);
        float v = bf2f(vs[(size_t)(700 + row0 + ql * LT + l) * OUTD + d]);
        e += v * v;
        int c = 0;
#pragma unroll
        for (int a = 0; a < 5; a++) {
            h[a] += v * pv[a];
#pragma unroll
            for (int b = a; b < 5; b++) g[c++] += pv[a] * pv[b];
        }
    }
    float vals[21];
#pragma unroll
    for (int k = 0; k < 15; k++) vals[k] = g[k];
#pragma unroll
    for (int k = 0; k < 5; k++) vals[15 + k] = h[k];
    vals[20] = e;
#pragma unroll
    for (int k = 0; k < 21; k++)
        for (int o = 32; o > 0; o >>= 1) vals[k] += __shfl_xor(vals[k], o);
    __shared__ float red[4][21];
    if (lane == 0)
#pragma unroll
        for (int k = 0; k < 21; k++) red[wave][k] = vals[k];
    __syncthreads();
    if (t < 21) {
        float s = red[0][t] + red[1][t] + red[2][t] + red[3][t];
        atomicAdd(&gbuf[(q0 + ql) * 21 + t], s);
    }
}

// ---------------------------------------------------------------------------
// out (fp32): per q -> 25 sim + 5 ori
// ---------------------------------------------------------------------------
__global__ __launch_bounds__(64) void out_k(const float* __restrict__ gbuf,
                                            float* __restrict__ out) {
    int q = blockIdx.x;
    if (threadIdx.x != 0) return;
    const float* r = gbuf + q * 21;
    float G[5][5];
    int c = 0;
    for (int a = 0; a < 5; a++)
        for (int b = a; b < 5; b++) { G[a][b] = r[c]; G[b][a] = r[c]; c++; }
    float e = r[20];
    float nrm[5];
    for (int a = 0; a < 5; a++) nrm[a] = sqrtf(fmaxf(G[a][a], 0.f));
    for (int a = 0; a < 5; a++)
        for (int b = 0; b < 5; b++)
            out[(size_t)q * 25 + a * 5 + b] = G[a][b] / fmaxf(nrm[a] * nrm[b], 1e-8f);
    for (int w = 0; w < 5; w++)
        out[5000 + (size_t)q * 5 + w] = -(e - 2.f * r[15 + w] + G[w][w]) * (1.f / 28.f);
}

// ---------------------------------------------------------------------------
extern "C" void kernel_launch(void* const* d_in, const int* in_sizes, int n_in,
                              void* d_out, int out_size, void* d_ws, size_t ws_size,
                              hipStream_t stream) {
    const float* sup = (const float*)d_in[0];
    // d_in[1] = support_labels int32 — unused (sorted equal-shot)
    const float* qry = (const float*)d_in[2];
    const float* k_w = (const float*)d_in[3];
    const float* k_b = (const float*)d_in[4];
    const float* v_w = (const float*)d_in[5];
    const float* v_b = (const float*)d_in[6];
    const float* lng = (const float*)d_in[7];
    const float* lnb = (const float*)d_in[8];
    (void)in_sizes; (void)n_in; (void)out_size; (void)ws_size;

    // layout (bytes), peak 49,421,728 (<= verified ws_size >= 54.5 MB):
    //   pexb   @0           7,864,320 (1920 rows; 1800 real)  dead after proj
    //   wbf    @7,864,320  18,874,368 (k|v bf16)              dead after proj
    //   Yk     @26,738,688  8,294,400 (1800x2304)             dead after comb_k
    //   Yv     @35,033,088  8,294,400                         dead after comb_v
    //   ks     @0          14,588,928 (6332 rows; 6300 real)  dead after scores
    //   vs     @16,220,160 14,515,200 (6300 rows)             live to end
    //   sc     @30,735,360  8,650,752 (over dead Yk/Yv head)  dead after softmax
    //   vsp    @39,386,112  1,843,200
    //   attn   @41,229,312  8,110,080 (5632 rows x 720; 5 x 144-col blocks)
    //   gbuf   @49,339,392     16,800
    //   pe     @49,356,192     65,536 (8x2048 fp32 table)
    //   protoc @0          16,220,160 (over dead ks, after scores)
    char* ws = (char*)d_ws;
    bf16* pexb   = (bf16*)(ws + 0);
    bf16* wbf    = (bf16*)(ws + 7864320);
    bf16* Yk     = (bf16*)(ws + 26738688);
    bf16* Yv     = (bf16*)(ws + 35033088);
    bf16* ks     = (bf16*)(ws + 0);
    bf16* vs     = (bf16*)(ws + 16220160);
    bf16* sc     = (bf16*)(ws + 30735360);
    bf16* vsp    = (bf16*)(ws + 39386112);
    bf16* attn   = (bf16*)(ws + 41229312);
    float* gbuf  = (float*)(ws + 49339392);
    float* pe    = (float*)(ws + 49356192);
    bf16* protoc = (bf16*)(ws + 0);

    pe_k<<<dim3(64), dim3(256), 0, stream>>>(pe);
    pex_k<<<dim3(1800), dim3(256), 0, stream>>>(sup, qry, pe, pexb);
    wconv2_k<<<dim3(9216), dim3(256), 0, stream>>>(
        (const float4*)k_w, (const float4*)v_w, (ushort4*)wbf);

    // fused K+V projection: z in {k,v}; Y[1800,2304] = pexb @ W_view^T
    gemm_bt<<<dim3(15, 18, 2), dim3(256), 0, stream>>>(
        pexb, DM, 0, wbf, DM, (size_t)4718592,
        1.0f, Yk, N2, (size_t)4147200, DM, 1800);

    combine_k<<<dim3(M_ALL), dim3(256), 0, stream>>>(
        (const unsigned int*)Yk, k_b, lng, lnb, ks);
    combine_v<<<dim3(M_ALL), dim3(256), 0, stream>>>(
        (const unsigned int*)Yv, v_b, vs);

    // scores: ks_q[5632,1152] @ ks_s[768,1152]^T / sqrt(1152)
    gemm_bt<<<dim3(44, 6, 1), dim3(256), 0, stream>>>(
        ks + (size_t)700 * OUTD, OUTD, 0, ks, OUTD, 0,
        0.029462782549439484f, sc, SN_PAD, 0, OUTD, 5632);

    vspad_k<<<dim3((5 * OUTD * KP + 255) / 256), dim3(256), 0, stream>>>(
        vs, vsp, gbuf);
    softmax_k<<<dim3(SM), dim3(256), 0, stream>>>(sc, attn);

    // proto chunks: 4 x 50 queries; per-class GEMM then Gram reduce
    // A = attn with 144-col class blocks (aZ=144, 16B-aligned); K=160 reads
    // spill 16 cols into the next block where vsp's zero columns kill them.
    for (int c = 0; c < 4; c++) {
        gemm_bt<<<dim3(11, 9, 5), dim3(256), 0, stream>>>(
            attn + (size_t)c * CH_ROWS * ATT_STRIDE, ATT_STRIDE, (size_t)ABLK,
            vsp, KP, (size_t)OUTD * KP,
            1.0f, protoc, OUTD, (size_t)CH_MPAD * OUTD, KP, CH_MPAD);
        gramred_k<<<dim3(CH_Q, 7), dim3(256), 0, stream>>>(
            protoc, vs, gbuf, c * CH_ROWS, c * CH_Q);
    }

    out_k<<<dim3(NQ), dim3(64), 0, stream>>>(gbuf, (float*)d_out);
}

// Round 5
// 343.817 us; speedup vs baseline: 1.2415x; 1.0951x over previous
//
#include <hip/hip_runtime.h>
#include <hip/hip_bf16.h>
#include <math.h>

typedef __hip_bfloat16 bf16;
typedef short s16x8 __attribute__((ext_vector_type(8)));
typedef float f32x4 __attribute__((ext_vector_type(4)));

#define NQ 200
#define SEQ 8
#define DM 2048
#define OUTD 1152
#define LT 28
#define M_ALL 6300
#define SM 5600
#define SN_PAD 768
#define ATT_STRIDE 720
#define N2 2304          // W viewed as [2304, 2048]
#define KP 160
#define CH_Q 50
#define CH_ROWS 1400
#define CH_MPAD 1408
#define ABLK 144         // attn per-class column block (16B-aligned)

__device__ __forceinline__ float bf2f(bf16 v) { return __bfloat162float(v); }
__device__ __forceinline__ bf16 f2bf(float v) { return __float2bfloat16(v); }
__device__ __forceinline__ float ubits2f(unsigned int u16) {
    unsigned int i = u16 << 16;
    float f; __builtin_memcpy(&f, &i, 4); return f;
}
__device__ __forceinline__ unsigned short f2bits(float f) {
    bf16 b = __float2bfloat16(f);
    unsigned short u; __builtin_memcpy(&u, &b, 2); return u;
}

__device__ const int TUP_A[LT] = {0,0,0,0,0,0,0,1,1,1,1,1,1,2,2,2,2,2,3,3,3,3,4,4,4,5,5,6};
__device__ const int TUP_B[LT] = {1,2,3,4,5,6,7,2,3,4,5,6,7,3,4,5,6,7,4,5,6,7,5,6,7,6,7,7};

// ---------------------------------------------------------------------------
// fused weight convert: [k_w | v_w] fp32 -> bf16 (2 x 1,179,648 float4)
// ---------------------------------------------------------------------------
__global__ __launch_bounds__(256) void wconv2_k(const float4* __restrict__ kw,
                                                const float4* __restrict__ vw,
                                                ushort4* __restrict__ o) {
    int i = blockIdx.x * 256 + threadIdx.x;     // 0 .. 2,359,295
    float4 v = (i < 1179648) ? kw[i] : vw[i - 1179648];
    ushort4 r;
    r.x = f2bits(v.x); r.y = f2bits(v.y); r.z = f2bits(v.z); r.w = f2bits(v.w);
    o[i] = r;
}

// ---------------------------------------------------------------------------
// pe table: pe[s][d], 8 x 2048 fp32 (trig computed once, not 1800x).
// Also zeroes attn tail rows 5600..5631 (never written by softmax; the proto
// GEMM's K-spill reads next-row cols 0..15, so uninit bf16 there could be
// NaN and NaN*0 would poison protoc row 1399).
// ---------------------------------------------------------------------------
__global__ __launch_bounds__(256) void pe_k(float* __restrict__ pe,
                                            bf16* __restrict__ attn_tail) {
    int i = blockIdx.x * 256 + threadIdx.x;     // 0 .. 16383
    int s = i >> 11, d = i & 2047;
    float dv = expf((float)(d & ~1) * (-9.210340371976184f / 2048.0f));
    float ang = (float)s * dv;
    pe[i] = (d & 1) ? cosf(ang) * 0.1f : sinf(ang) * 0.1f;
    for (int j = i; j < 32 * ATT_STRIDE; j += 64 * 256) attn_tail[j] = f2bf(0.f);
}

// ---------------------------------------------------------------------------
// pexb[r][d] = fp32 src[n][s][d] + pe[s][d] -> bf16 (1800 rows, vectorized)
// ---------------------------------------------------------------------------
__global__ __launch_bounds__(256) void pex_k(const float* __restrict__ sup,
                                             const float* __restrict__ qry,
                                             const float* __restrict__ pe,
                                             bf16* __restrict__ pexb) {
    int r = blockIdx.x, t = threadIdx.x;
    int n, s;
    const float* src;
    if (r < 200) { n = r >> 3; s = r & 7; src = sup; }
    else { int rr = r - 200; n = rr >> 3; s = rr & 7; src = qry; }
    const float4* row = (const float4*)(src + ((size_t)n * SEQ + s) * DM);
    const float4* per = (const float4*)(pe + (size_t)s * DM);
    ushort4* orow = (ushort4*)(pexb + (size_t)r * DM);
    for (int d = t; d < DM / 4; d += 256) {
        float4 a = row[d], p = per[d];
        ushort4 o;
        o.x = f2bits(a.x + p.x); o.y = f2bits(a.y + p.y);
        o.z = f2bits(a.z + p.z); o.w = f2bits(a.w + p.w);
        orow[d] = o;
    }
}

// ---------------------------------------------------------------------------
// Generic MFMA bf16 GEMM: C = scale*A*B^T; z shifts A/B/C by aZ/bZ/cZ elems.
// Register-staged (global->VGPR->LDS) with DOUBLE-BUFFERED LDS and exactly
// ONE __syncthreads() per 32-K step: the staged write targets the buffer the
// current COMPUTE is NOT reading, so no "readers done" barrier is needed;
// the single barrier makes the write visible before the next step's reads.
// GLOAD for tile s+1 is issued one step ahead (single reg buffer, WAR-ordered
// against its LDSW), giving every load a full COMPUTE+barrier of slack.
// [history: single-buffer 2-barrier = 74.8us; gload_lds variants 116/128us
//  (conservative vmcnt drain); 2-deep reg prefetch 86.5us (VGPR 104).]
// XCD-chunked bijective block swizzle (T1/m204) kept: FETCH 104->50 MB.
// Requires K >= 32; C rows >= mlim are not stored (M-pad containment).
// ---------------------------------------------------------------------------
__global__ __launch_bounds__(256) void gemm_bt(
    const bf16* __restrict__ A, int lda, size_t aZ,
    const bf16* __restrict__ B, int ldb, size_t bZ,
    float scale, bf16* __restrict__ C, int ldc, size_t cZ, int K, int mlim) {
    // ---- XCD swizzle: logical tile id lg from hw block id (bijective) ----
    const int gx = gridDim.x, gy = gridDim.y;
    const int nwg = gx * gy * (int)gridDim.z;
    const int orig = ((int)blockIdx.z * gy + blockIdx.y) * gx + blockIdx.x;
    const int qc = nwg >> 3, rc = nwg & 7;
    const int xcd = orig & 7, sub = orig >> 3;
    const int lg = (xcd < rc ? xcd * (qc + 1) : rc * (qc + 1) + (xcd - rc) * qc) + sub;
    const int bx = lg % gx;
    const int rest = lg / gx;
    const int by = rest % gy, bz = rest / gy;

    const unsigned short* Ag0 = (const unsigned short*)A + aZ * bz;
    const unsigned short* Bg0 = (const unsigned short*)B + bZ * bz;
    const size_t cbase = cZ * bz;
    const int tile_m = bx * 128, tile_n = by * 128;
    __shared__ unsigned short A0s[4096];   // 8 KB each; 32 KB total
    __shared__ unsigned short A1s[4096];
    __shared__ unsigned short B0s[4096];
    __shared__ unsigned short B1s[4096];
    const int t = threadIdx.x, lane = t & 63, wave = t >> 6;
    const int wm = (wave & 1) * 64, wn = (wave >> 1) * 64;
    const int srow = t >> 1, sq0 = (t & 1) * 2;
    const unsigned short* Ag = Ag0 + (size_t)(tile_m + srow) * lda + (t & 1) * 16;
    const unsigned short* Bg = Bg0 + (size_t)(tile_n + srow) * ldb + (t & 1) * 16;
    const int offW0 = ((sq0 + 0) * 128 + srow) * 8;
    const int offW1 = ((sq0 + 1) * 128 + srow) * 8;
    const int fr = lane & 15, quad = lane >> 4;

    f32x4 acc[4][4];
#pragma unroll
    for (int i = 0; i < 4; i++)
#pragma unroll
        for (int j = 0; j < 4; j++) acc[i][j] = {0.f, 0.f, 0.f, 0.f};

    uint4 ra0, ra1, rb0, rb1;
#define GLOAD(k0) do {                                                          \
    ra0 = *(const uint4*)(Ag + (k0));  ra1 = *(const uint4*)(Ag + (k0) + 8);    \
    rb0 = *(const uint4*)(Bg + (k0));  rb1 = *(const uint4*)(Bg + (k0) + 8);    \
  } while (0)

#define LDSW(AS, BS) do {                                                       \
    *(uint4*)&AS[offW0] = ra0; *(uint4*)&AS[offW1] = ra1;                       \
    *(uint4*)&BS[offW0] = rb0; *(uint4*)&BS[offW1] = rb1;                       \
  } while (0)

#define COMPUTE(AS, BS) do {                                                    \
    s16x8 af[4], bfv[4];                                                        \
    _Pragma("unroll")                                                           \
    for (int i = 0; i < 4; i++)                                                 \
        af[i] = *(const s16x8*)&AS[(quad * 128 + wm + i * 16 + fr) * 8];        \
    _Pragma("unroll")                                                           \
    for (int j = 0; j < 4; j++)                                                 \
        bfv[j] = *(const s16x8*)&BS[(quad * 128 + wn + j * 16 + fr) * 8];       \
    _Pragma("unroll")                                                           \
    for (int i = 0; i < 4; i++)                                                 \
    _Pragma("unroll")                                                           \
        for (int j = 0; j < 4; j++)                                             \
            acc[i][j] = __builtin_amdgcn_mfma_f32_16x16x32_bf16(af[i], bfv[j], acc[i][j], 0, 0, 0); \
  } while (0)

    const int nIter = K >> 5;              // 32-K tiles; invariant at top of
    GLOAD(0);                              // body s: buf0 = tile s, regs = s+1
    LDSW(A0s, B0s);
    if (nIter > 1) GLOAD(32);
    __syncthreads();
    for (int s = 0; s < nIter; s += 2) {   // all guards wave-uniform
        if (s + 1 < nIter) LDSW(A1s, B1s);         // buf1 <- tile s+1
        if (s + 2 < nIter) GLOAD((s + 2) * 32);    // regs <- tile s+2
        COMPUTE(A0s, B0s);                          // compute tile s
        __syncthreads();
        if (s + 1 < nIter) {
            if (s + 2 < nIter) LDSW(A0s, B0s);     // buf0 <- tile s+2
            if (s + 3 < nIter) GLOAD((s + 3) * 32);
            COMPUTE(A1s, B1s);                      // compute tile s+1
            __syncthreads();
        }
    }
#undef GLOAD
#undef LDSW
#undef COMPUTE

    const int rb = quad * 4;
#pragma unroll
    for (int i = 0; i < 4; i++)
#pragma unroll
        for (int j = 0; j < 4; j++) {
            const int col = tile_n + wn + j * 16 + fr;
#pragma unroll
            for (int r = 0; r < 4; r++) {
                const int row = tile_m + wm + i * 16 + rb + r;
                if (row < mlim)
                    C[cbase + (size_t)row * ldc + col] = f2bf(acc[i][j][r] * scale);
            }
        }
}

// ---------------------------------------------------------------------------
// combine_k: ks[m][n] = LN(Yk[ra][2n] + Yk[rb][2n+1] + kb[n])
// ---------------------------------------------------------------------------
__global__ __launch_bounds__(256) void combine_k(
    const unsigned int* __restrict__ Yk, const float* __restrict__ kb,
    const float* __restrict__ lng, const float* __restrict__ lnb,
    bf16* __restrict__ ks) {
    const int m = blockIdx.x, t = threadIdx.x, lane = t & 63, wave = t >> 6;
    int mm = m < 700 ? m : m - 700;
    int base = m < 700 ? 0 : 200;
    int nsamp = mm / LT, l = mm - nsamp * LT;
    const unsigned int* ya = Yk + (size_t)(base + nsamp * 8 + TUP_A[l]) * (N2 / 2);
    const unsigned int* yb = Yk + (size_t)(base + nsamp * 8 + TUP_B[l]) * (N2 / 2);
    float vals[5];
    int cnt = 0;
    float s = 0.f, s2 = 0.f;
    for (int n = t; n < OUTD; n += 256) {
        unsigned int ua = ya[n], ub = yb[n];
        float vk = ubits2f(ua & 0xFFFFu) + ubits2f(ub >> 16) + kb[n];
        vals[cnt++] = vk;
        s += vk; s2 += vk * vk;
    }
    for (int o = 32; o > 0; o >>= 1) { s += __shfl_xor(s, o); s2 += __shfl_xor(s2, o); }
    __shared__ float r1[4], r2[4];
    if (lane == 0) { r1[wave] = s; r2[wave] = s2; }
    __syncthreads();
    s = r1[0] + r1[1] + r1[2] + r1[3];
    s2 = r2[0] + r2[1] + r2[2] + r2[3];
    float mu = s * (1.f / OUTD);
    float var = s2 * (1.f / OUTD) - mu * mu;
    float inv = rsqrtf(fmaxf(var, 0.f) + 1e-5f);
    cnt = 0;
    for (int n = t; n < OUTD; n += 256)
        ks[(size_t)m * OUTD + n] = f2bf((vals[cnt++] - mu) * inv * lng[n] + lnb[n]);
}

// ---------------------------------------------------------------------------
// combine_v: vs[m][n] = Yv[ra][2n] + Yv[rb][2n+1] + vb[n]
// ---------------------------------------------------------------------------
__global__ __launch_bounds__(256) void combine_v(
    const unsigned int* __restrict__ Yv, const float* __restrict__ vb,
    bf16* __restrict__ vs) {
    const int m = blockIdx.x, t = threadIdx.x;
    int mm = m < 700 ? m : m - 700;
    int base = m < 700 ? 0 : 200;
    int nsamp = mm / LT, l = mm - nsamp * LT;
    const unsigned int* ya = Yv + (size_t)(base + nsamp * 8 + TUP_A[l]) * (N2 / 2);
    const unsigned int* yb = Yv + (size_t)(base + nsamp * 8 + TUP_B[l]) * (N2 / 2);
    for (int n = t; n < OUTD; n += 256) {
        unsigned int ua = ya[n], ub = yb[n];
        vs[(size_t)m * OUTD + n] =
            f2bf(ubits2f(ua & 0xFFFFu) + ubits2f(ub >> 16) + vb[n]);
    }
}

// ---------------------------------------------------------------------------
// softmax: one WAVE per (row, class): 140 = 64+64+12 elems/lane-slot; pure
// 64-lane shuffle reductions, ZERO barriers (was ~15 __syncthreads/block).
// attn laid out as 5 x 144-col blocks; cols 140..143 of each block zeroed.
// ---------------------------------------------------------------------------
__global__ __launch_bounds__(320) void softmax_k(const bf16* __restrict__ sc,
                                                 bf16* __restrict__ attn) {
    const int row = blockIdx.x, w = threadIdx.x >> 6, lane = threadIdx.x & 63;
    const bf16* src = sc + (size_t)row * SN_PAD + w * 140;
    bf16* dst = attn + (size_t)row * ATT_STRIDE + w * ABLK;
    float a = bf2f(src[lane]);
    float b = bf2f(src[lane + 64]);            // lane+64 <= 127 < 140: valid
    float c = (lane < 12) ? bf2f(src[lane + 128]) : -3.0e38f;
    float m = fmaxf(fmaxf(a, b), c);
    for (int o = 32; o > 0; o >>= 1) m = fmaxf(m, __shfl_xor(m, o));
    float ea = __expf(a - m), eb = __expf(b - m);
    float ec = (lane < 12) ? __expf(c - m) : 0.f;
    float s = ea + eb + ec;
    for (int o = 32; o > 0; o >>= 1) s += __shfl_xor(s, o);
    float inv = 1.f / s;
    dst[lane] = f2bf(ea * inv);
    dst[lane + 64] = f2bf(eb * inv);
    if (lane < 16) dst[lane + 128] = f2bf(lane < 12 ? ec * inv : 0.f);
}

// ---------------------------------------------------------------------------
// vsp[w][d][j] = vs[w*140+j][d] (j>=140 -> 0); block 0 also zeroes gbuf
// ---------------------------------------------------------------------------
__global__ __launch_bounds__(256) void vspad_k(const bf16* __restrict__ vs,
                                               bf16* __restrict__ vp,
                                               float* __restrict__ gbuf) {
    int idx = blockIdx.x * 256 + threadIdx.x;
    if (blockIdx.x == 0)
        for (int i = threadIdx.x; i < NQ * 21; i += 256) gbuf[i] = 0.f;
    if (idx >= 5 * OUTD * KP) return;
    int j = idx % KP;
    int rest = idx / KP;
    int dcol = rest % OUTD;
    int w = rest / OUTD;
    vp[idx] = (j < 140) ? vs[(size_t)(w * 140 + j) * OUTD + dcol] : f2bf(0.f);
}

// ---------------------------------------------------------------------------
// Gram reduce over a proto chunk -> 21 sufficient stats per query.
// Vectorized: s16x8 (16B) loads, 2 tuple-rows per block, grid (50,14).
// Rows are 1152 bf16 = 2304 B (16B-aligned), so 16B loads are safe.
// ---------------------------------------------------------------------------
__global__ __launch_bounds__(256) void gramred_k(const bf16* __restrict__ protoc,
                                                 const bf16* __restrict__ vs,
                                                 float* __restrict__ gbuf,
                                                 int row0, int q0) {
    const int ql = blockIdx.x;          // 0..49
    const int lgb = blockIdx.y;         // 0..13 (2 tuple-rows each)
    const int t = threadIdx.x, lane = t & 63, wave = t >> 6;
    const size_t PZ = (size_t)CH_MPAD * OUTD;
    float g[15] = {0.f};
    float h[5] = {0.f, 0.f, 0.f, 0.f, 0.f};
    float e = 0.f;
    for (int idx = t; idx < 2 * OUTD / 8; idx += 256) {   // 288 16B-slots
        int li = idx / 144;
        int dv = idx - li * 144;
        int l = lgb * 2 + li;
        size_t ml = (size_t)(ql * LT + l) * OUTD + dv * 8;
        s16x8 pw0 = *(const s16x8*)&protoc[0 * PZ + ml];
        s16x8 pw1 = *(const s16x8*)&protoc[1 * PZ + ml];
        s16x8 pw2 = *(const s16x8*)&protoc[2 * PZ + ml];
        s16x8 pw3 = *(const s16x8*)&protoc[3 * PZ + ml];
        s16x8 pw4 = *(const s16x8*)&protoc[4 * PZ + ml];
        s16x8 vv = *(const s16x8*)&vs[(size_t)(700 + row0 + ql * LT + l) * OUTD + dv * 8];
#pragma unroll
        for (int ee = 0; ee < 8; ee++) {
            float pv[5];
            pv[0] = ubits2f((unsigned short)pw0[ee]);
            pv[1] = ubits2f((unsigned short)pw1[ee]);
            pv[2] = ubits2f((unsigned short)pw2[ee]);
            pv[3] = ubits2f((unsigned short)pw3[ee]);
            pv[4] = ubits2f((unsigned short)pw4[ee]);
            float v = ubits2f((unsigned short)vv[ee]);
            e += v * v;
            int c = 0;
#pragma unroll
            for (int a = 0; a < 5; a++) {
                h[a] += v * pv[a];
#pragma unroll
                for (int b = a; b < 5; b++) g[c++] += pv[a] * pv[b];
            }
        }
    }
    float vals[21];
#pragma unroll
    for (int k = 0; k < 15; k++) vals[k] = g[k];
#pragma unroll
    for (int k = 0; k < 5; k++) vals[15 + k] = h[k];
    vals[20] = e;
#pragma unroll
    for (int k = 0; k < 21; k++)
        for (int o = 32; o > 0; o >>= 1) vals[k] += __shfl_xor(vals[k], o);
    __shared__ float red[4][21];
    if (lane == 0)
#pragma unroll
        for (int k = 0; k < 21; k++) red[wave][k] = vals[k];
    __syncthreads();
    if (t < 21) {
        float s = red[0][t] + red[1][t] + red[2][t] + red[3][t];
        atomicAdd(&gbuf[(q0 + ql) * 21 + t], s);
    }
}

// ---------------------------------------------------------------------------
// out (fp32): per q -> 25 sim + 5 ori
// ---------------------------------------------------------------------------
__global__ __launch_bounds__(64) void out_k(const float* __restrict__ gbuf,
                                            float* __restrict__ out) {
    int q = blockIdx.x;
    if (threadIdx.x != 0) return;
    const float* r = gbuf + q * 21;
    float G[5][5];
    int c = 0;
    for (int a = 0; a < 5; a++)
        for (int b = a; b < 5; b++) { G[a][b] = r[c]; G[b][a] = r[c]; c++; }
    float e = r[20];
    float nrm[5];
    for (int a = 0; a < 5; a++) nrm[a] = sqrtf(fmaxf(G[a][a], 0.f));
    for (int a = 0; a < 5; a++)
        for (int b = 0; b < 5; b++)
            out[(size_t)q * 25 + a * 5 + b] = G[a][b] / fmaxf(nrm[a] * nrm[b], 1e-8f);
    for (int w = 0; w < 5; w++)
        out[5000 + (size_t)q * 5 + w] = -(e - 2.f * r[15 + w] + G[w][w]) * (1.f / 28.f);
}

// ---------------------------------------------------------------------------
extern "C" void kernel_launch(void* const* d_in, const int* in_sizes, int n_in,
                              void* d_out, int out_size, void* d_ws, size_t ws_size,
                              hipStream_t stream) {
    const float* sup = (const float*)d_in[0];
    // d_in[1] = support_labels int32 — unused (sorted equal-shot)
    const float* qry = (const float*)d_in[2];
    const float* k_w = (const float*)d_in[3];
    const float* k_b = (const float*)d_in[4];
    const float* v_w = (const float*)d_in[5];
    const float* v_b = (const float*)d_in[6];
    const float* lng = (const float*)d_in[7];
    const float* lnb = (const float*)d_in[8];
    (void)in_sizes; (void)n_in; (void)out_size; (void)ws_size;

    // layout (bytes), peak 49,421,728 (<= verified ws_size >= 54.5 MB):
    //   pexb   @0           7,864,320 (1920 rows; 1800 real)  dead after proj
    //   wbf    @7,864,320  18,874,368 (k|v bf16)              dead after proj
    //   Yk     @26,738,688  8,294,400 (1800x2304)             dead after comb_k
    //   Yv     @35,033,088  8,294,400                         dead after comb_v
    //   ks     @0          14,588,928 (6332 rows; 6300 real)  dead after scores
    //   vs     @16,220,160 14,515,200 (6300 rows)             live to end
    //   sc     @30,735,360  8,650,752 (over dead Yk/Yv head)  dead after softmax
    //   vsp    @39,386,112  1,843,200
    //   attn   @41,229,312  8,110,080 (5632 rows x 720; 5 x 144-col blocks)
    //   gbuf   @49,339,392     16,800
    //   pe     @49,356,192     65,536 (8x2048 fp32 table)
    //   protoc @0          16,220,160 (over dead ks, after scores)
    char* ws = (char*)d_ws;
    bf16* pexb   = (bf16*)(ws + 0);
    bf16* wbf    = (bf16*)(ws + 7864320);
    bf16* Yk     = (bf16*)(ws + 26738688);
    bf16* Yv     = (bf16*)(ws + 35033088);
    bf16* ks     = (bf16*)(ws + 0);
    bf16* vs     = (bf16*)(ws + 16220160);
    bf16* sc     = (bf16*)(ws + 30735360);
    bf16* vsp    = (bf16*)(ws + 39386112);
    bf16* attn   = (bf16*)(ws + 41229312);
    float* gbuf  = (float*)(ws + 49339392);
    float* pe    = (float*)(ws + 49356192);
    bf16* protoc = (bf16*)(ws + 0);

    pe_k<<<dim3(64), dim3(256), 0, stream>>>(pe, attn + (size_t)SM * ATT_STRIDE);
    pex_k<<<dim3(1800), dim3(256), 0, stream>>>(sup, qry, pe, pexb);
    wconv2_k<<<dim3(9216), dim3(256), 0, stream>>>(
        (const float4*)k_w, (const float4*)v_w, (ushort4*)wbf);

    // fused K+V projection: z in {k,v}; Y[1800,2304] = pexb @ W_view^T
    gemm_bt<<<dim3(15, 18, 2), dim3(256), 0, stream>>>(
        pexb, DM, 0, wbf, DM, (size_t)4718592,
        1.0f, Yk, N2, (size_t)4147200, DM, 1800);

    combine_k<<<dim3(M_ALL), dim3(256), 0, stream>>>(
        (const unsigned int*)Yk, k_b, lng, lnb, ks);
    combine_v<<<dim3(M_ALL), dim3(256), 0, stream>>>(
        (const unsigned int*)Yv, v_b, vs);

    // scores: ks_q[5632,1152] @ ks_s[768,1152]^T / sqrt(1152)
    gemm_bt<<<dim3(44, 6, 1), dim3(256), 0, stream>>>(
        ks + (size_t)700 * OUTD, OUTD, 0, ks, OUTD, 0,
        0.029462782549439484f, sc, SN_PAD, 0, OUTD, 5632);

    vspad_k<<<dim3((5 * OUTD * KP + 255) / 256), dim3(256), 0, stream>>>(
        vs, vsp, gbuf);
    softmax_k<<<dim3(SM), dim3(320), 0, stream>>>(sc, attn);

    // proto chunks: 4 x 50 queries; per-class GEMM then Gram reduce
    // A = attn with 144-col class blocks (aZ=144, 16B-aligned); K=160 reads
    // spill 16 cols into the next block where vsp's zero columns kill them.
    for (int c = 0; c < 4; c++) {
        gemm_bt<<<dim3(11, 9, 5), dim3(256), 0, stream>>>(
            attn + (size_t)c * CH_ROWS * ATT_STRIDE, ATT_STRIDE, (size_t)ABLK,
            vsp, KP, (size_t)OUTD * KP,
            1.0f, protoc, OUTD, (size_t)CH_MPAD * OUTD, KP, CH_MPAD);
        gramred_k<<<dim3(CH_Q, 14), dim3(256), 0, stream>>>(
            protoc, vs, gbuf, c * CH_ROWS, c * CH_Q);
    }

    out_k<<<dim3(NQ), dim3(64), 0, stream>>>(gbuf, (float*)d_out);
}